// Round 3
// baseline (976.882 us; speedup 1.0000x reference)
//
#include <hip/hip_runtime.h>

// GRU scan: B=2048, T=2048, D=3, H=32. out[b,t] = h_new[b,t][0].
// Round-6: register-resident h, ZERO LDS. R5 post-mortem: only ~47% VALU
// issue duty; the stall is the per-step LDS write->read h-exchange under
// 8-wave/CU contention. This round keeps h in registers:
//  - 64 lanes = 4 rows of 16. row r, pos p: carries h[16*(r&1)+p],
//    computes gates for unit o=p+16*(r>>1); gate (r vs z) = r&1.
//  - h all-gather within each row: 15 v_mov_dpp row_ror:j (VALU pipe),
//    weights pre-permuted per lane so FMA j uses rotation j. Rotation
//    direction probed at runtime; weight load indices adapt.
//  - K-half combine + r/z exchange: permlane16_swap (lane^16 pairs);
//    carried-h fix-up: permlane32_swap (lane^32) — both probed per-lane
//    (ballot-verified), ds_bpermute fallback variant if any probe fails.
//  - x: one float3 per lane per 64-step chunk (coalesced, prefetched);
//    per-step broadcast via v_readlane. Output via readfirstlane+select.

#define GRU_B 2048
#define GRU_T 2048
#define GRU_D 3
#define GRU_H 32
#define CHUNK 64  // timesteps per chunk: one x float3 per lane

#if __has_builtin(__builtin_amdgcn_permlane16_swap) && \
    __has_builtin(__builtin_amdgcn_permlane32_swap) && \
    __has_builtin(__builtin_amdgcn_update_dpp)
#define HAVE_FAST 1
#else
#define HAVE_FAST 0
#endif

typedef unsigned int uint2v __attribute__((ext_vector_type(2)));

__device__ __forceinline__ float fast_sigmoid(float x) {
    float e = __expf(-x);                    // v_mul(log2e)+v_exp
    return __builtin_amdgcn_rcpf(1.0f + e);  // e=inf -> 0 (correct limit)
}
__device__ __forceinline__ float fast_tanh(float x) {
    float e = __expf(2.0f * x);              // overflow -> inf -> tanh=1
    return 1.0f - 2.0f * __builtin_amdgcn_rcpf(e + 1.0f);
}
__device__ __forceinline__ float bperm(float v, int baddr) {
    return __int_as_float(__builtin_amdgcn_ds_bpermute(baddr, __float_as_int(v)));
}

#if HAVE_FAST
// DPP row_ror:N = 0x120+N; full row/bank masks, no bound ctrl.
#define DPPF(v, CTRL) __int_as_float(__builtin_amdgcn_update_dpp( \
    0, __float_as_int(v), (CTRL), 0xF, 0xF, false))
#endif

// lane^16 exchange: permlane16_swap (VALU) or ds_bpermute fallback.
template<bool FAST>
__device__ __forceinline__ float xsw16(float v, bool sel, int a16) {
#if HAVE_FAST
    if constexpr (FAST) {
        uint2v r = __builtin_amdgcn_permlane16_swap(
            __float_as_uint(v), __float_as_uint(v), false, false);
        return __uint_as_float(sel ? r.x : r.y);
    }
#endif
    return bperm(v, a16);
}
// lane^32 exchange.
template<bool FAST>
__device__ __forceinline__ float xsw32(float v, bool sel, int a32) {
#if HAVE_FAST
    if constexpr (FAST) {
        uint2v r = __builtin_amdgcn_permlane32_swap(
            __float_as_uint(v), __float_as_uint(v), false, false);
        return __uint_as_float(sel ? r.x : r.y);
    }
#endif
    return bperm(v, a32);
}

template<bool FAST>
__device__ __forceinline__ void gru_loop(
    const float* __restrict__ xb, float* __restrict__ ob,
    const float* wsA, const float* wsB, const float* wsC,
    const float* wiA, const float* wiC, float bA, float bC,
    int lane, bool g, bool sel16, bool sel32, bool m12,
    int a16, int a32, int p)
{
    // bpermute rotation addresses (safe path only): value needed at pos p,
    // rot j = value carried by lane (rowbase | (p+j)&15).
    int ra[16];
    if constexpr (!FAST) {
#pragma unroll
        for (int j = 0; j < 16; ++j)
            ra[j] = ((lane & 48) | ((p + j) & 15)) << 2;
    }

    float h = 0.0f;  // carried h[16*(r&1) + p]
    float3 xc = *(const float3*)(xb + (size_t)lane * 3);

    for (int c = 0; c < GRU_T / CHUNK; ++c) {
        float3 xn = xc;
        if (c + 1 < GRU_T / CHUNK)
            xn = *(const float3*)(xb + ((size_t)(c + 1) * CHUNK + lane) * 3);
        float outreg = 0.0f;

#pragma unroll 8
        for (int s = 0; s < CHUNK; ++s) {
            // x broadcast: lane s holds x(t=c*64+s, 0..2)
            const float x0 = __int_as_float(__builtin_amdgcn_readlane(__float_as_int(xc.x), s));
            const float x1 = __int_as_float(__builtin_amdgcn_readlane(__float_as_int(xc.y), s));
            const float x2 = __int_as_float(__builtin_amdgcn_readlane(__float_as_int(xc.z), s));

            // h all-gather within row: 15 DPP rotations (VALU pipe)
            float hr[16];
            hr[0] = h;
            if constexpr (FAST) {
#if HAVE_FAST
                hr[1]  = DPPF(h, 0x121); hr[2]  = DPPF(h, 0x122);
                hr[3]  = DPPF(h, 0x123); hr[4]  = DPPF(h, 0x124);
                hr[5]  = DPPF(h, 0x125); hr[6]  = DPPF(h, 0x126);
                hr[7]  = DPPF(h, 0x127); hr[8]  = DPPF(h, 0x128);
                hr[9]  = DPPF(h, 0x129); hr[10] = DPPF(h, 0x12A);
                hr[11] = DPPF(h, 0x12B); hr[12] = DPPF(h, 0x12C);
                hr[13] = DPPF(h, 0x12D); hr[14] = DPPF(h, 0x12E);
                hr[15] = DPPF(h, 0x12F);
#endif
            } else {
#pragma unroll
                for (int j = 1; j < 16; ++j) hr[j] = bperm(h, ra[j]);
            }

            // input projections (off critical path)
            const float aM = fmaf(wiA[2], x2, fmaf(wiA[1], x1, fmaf(wiA[0], x0, bA)));
            const float aN = fmaf(wiC[2], x2, fmaf(wiC[1], x1, fmaf(wiC[0], x0, bC)));

            // K-half partials over pre-permuted weights: A (my sigmoid gate,
            // init aM), B (partner's gate, to send), C (n gate)
            float A0 = aM, A1 = 0.f, B0 = 0.f, B1 = 0.f, C0 = 0.f, C1 = 0.f;
#pragma unroll
            for (int j = 0; j < 16; j += 2) {
                A0 = fmaf(wsA[j],   hr[j],   A0);
                A1 = fmaf(wsA[j+1], hr[j+1], A1);
                B0 = fmaf(wsB[j],   hr[j],   B0);
                B1 = fmaf(wsB[j+1], hr[j+1], B1);
                C0 = fmaf(wsC[j],   hr[j],   C0);
                C1 = fmaf(wsC[j+1], hr[j+1], C1);
            }
            const float Bp = B0 + B1;
            const float Cp = C0 + C1;
            const float gM = (A0 + A1) + xsw16<FAST>(Bp, sel16, a16);
            const float gN = Cp + xsw16<FAST>(Cp, sel16, a16);

            // h_prev[o]: rows 1,2 carry the other K-half's unit -> take
            // partner's (lane^16) carried h.
            const float hx = xsw16<FAST>(h, sel16, a16);
            const float hprev = m12 ? hx : h;

            const float sg  = fast_sigmoid(gM);            // g=0: r, g=1: z
            const float zsw = xsw16<FAST>(sg, sel16, a16); // the other gate
            const float rr = g ? zsw : sg;
            const float zz = g ? sg : zsw;
            const float n  = fast_tanh(fmaf(rr, gN, aN));
            const float hnw = fmaf(zz, hprev - n, n);      // (1-z)*n + z*h

            // out[t] = h_new[t][0]; lane0 (row0,p0) computes o=0.
            const float h0 = __uint_as_float(
                __builtin_amdgcn_readfirstlane(__float_as_uint(hnw)));
            outreg = (lane == s) ? h0 : outreg;

            // carry fix-up: rows 1,2 need the unit matching their carried
            // K-slot, computed by their lane^32 partner (rows 3,0).
            const float hsw = xsw32<FAST>(hnw, sel32, a32);
            h = m12 ? hsw : hnw;
        }
        ob[c * CHUNK + lane] = outreg;  // 64 lanes, 256B coalesced
        xc = xn;
    }
}

__global__ __launch_bounds__(64, 2) void gru_scan_kernel(
    const float* __restrict__ inp,     // [B, T, D]
    const float* __restrict__ w_ih,    // [3H, D]
    const float* __restrict__ w_hh,    // [3H, H]
    const float* __restrict__ bias,    // [3H]
    const float* __restrict__ bias_n,  // [H]
    float* __restrict__ out)           // [B, T]
{
    const int lane = threadIdx.x;     // 0..63
    const int p = lane & 15;          // position within 16-lane row
    const int r = lane >> 4;          // row 0..3
    const int gi = r & 1;             // 0: r-gate rows, 1: z-gate rows
    const bool g = gi != 0;
    const int o = p + 16 * (r >> 1);  // output unit owned
    const bool m12 = (r == 1) || (r == 2);
    const int b = blockIdx.x;
    const int a16 = (lane ^ 16) << 2; // bpermute fallback addrs
    const int a32 = (lane ^ 32) << 2;

    // ---- one-time probes: permlane16/32_swap selection + DPP direction ----
    bool fast = false, sel16 = false, sel32 = false;
    int dir = 1;
#if HAVE_FAST
    {
        const unsigned ul = (unsigned)lane;
        uint2v q16 = __builtin_amdgcn_permlane16_swap(ul, ul, false, false);
        const unsigned w16 = ul ^ 16u;
        sel16 = (q16.x == w16);
        const bool ok16 = __ballot((q16.x == w16) || (q16.y == w16)) == ~0ULL;

        uint2v q32 = __builtin_amdgcn_permlane32_swap(ul, ul, false, false);
        const unsigned w32 = ul ^ 32u;
        sel32 = (q32.x == w32);
        const bool ok32 = __ballot((q32.x == w32) || (q32.y == w32)) == ~0ULL;

        const int d1 = __builtin_amdgcn_update_dpp(0, p, 0x121, 0xF, 0xF, false);
        bool okd = false;
        if (__ballot(d1 == ((p + 1) & 15)) == ~0ULL)       { okd = true; dir = 1; }
        else if (__ballot(d1 == ((p + 15) & 15)) == ~0ULL) { okd = true; dir = -1; }

        fast = ok16 && ok32 && okd;
    }
#endif

    // ---- weights: systolically pre-permuted so FMA j pairs rotation j ----
    const int rowA = 32 * gi + o;        // my sigmoid gate row
    const int rowB = 32 * (1 - gi) + o;  // partner's sigmoid gate row
    const int rowC = 2 * GRU_H + o;      // n gate row
    const int kb = 16 * gi;              // this row's K-range base (==16*(r&1))
    float wsA[16], wsB[16], wsC[16];
#pragma unroll
    for (int j = 0; j < 16; ++j) {
        const int kk = kb + ((p + dir * j + 16) & 15);
        wsA[j] = w_hh[rowA * GRU_H + kk];
        wsB[j] = w_hh[rowB * GRU_H + kk];
        wsC[j] = w_hh[rowC * GRU_H + kk];
    }
    float wiA[GRU_D], wiC[GRU_D];
#pragma unroll
    for (int d = 0; d < GRU_D; ++d) {
        wiA[d] = w_ih[rowA * GRU_D + d];
        wiC[d] = w_ih[rowC * GRU_D + d];
    }
    const float bA = bias[rowA];
    const float bC = bias[rowC] + bias_n[o];

    const float* xb = inp + (size_t)b * GRU_T * GRU_D;
    float*       ob = out + (size_t)b * GRU_T;

#if HAVE_FAST
    if (fast) {
        gru_loop<true>(xb, ob, wsA, wsB, wsC, wiA, wiC, bA, bC,
                       lane, g, sel16, sel32, m12, a16, a32, p);
        return;
    }
#endif
    gru_loop<false>(xb, ob, wsA, wsB, wsC, wiA, wiC, bA, bC,
                    lane, g, sel16, sel32, m12, a16, a32, p);
}

extern "C" void kernel_launch(void* const* d_in, const int* in_sizes, int n_in,
                              void* d_out, int out_size, void* d_ws, size_t ws_size,
                              hipStream_t stream) {
    const float* inp    = (const float*)d_in[0];
    const float* w_ih   = (const float*)d_in[1];
    const float* w_hh   = (const float*)d_in[2];
    const float* bias   = (const float*)d_in[3];
    const float* bias_n = (const float*)d_in[4];
    float* out = (float*)d_out;

    dim3 grid(GRU_B);
    dim3 block(64);
    gru_scan_kernel<<<grid, block, 0, stream>>>(inp, w_ih, w_hh, bias, bias_n, out);
}

// Round 4
// 640.680 us; speedup vs baseline: 1.5248x; 1.5248x over previous
//
#include <hip/hip_runtime.h>

// GRU scan: B=2048, T=2048, D=3, H=32. out[b,t] = h_new[b,t][0].
// Round-7: TWO sequences per wave, shared instruction stream.
// R3/R5/R6 post-mortem: with 1 seq/wave (2 waves/SIMD) every structure
// stalls at ~47% real issue duty on the serial recurrence; neither LDS nor
// DPP exchange changes it. Fix the chain/issue ratio instead:
//  - lanes 0-31 = seq 2b, lanes 32-63 = seq 2b+1, same instructions;
//    each lane owns ONE unit fully (r,z,n rows, K=32 -> 96 FMA) so there
//    are no cross-lane combines at all; h is a true per-lane trajectory.
//  - h exchange: R5-verified LDS pattern, waitless same-wave DS ordering.
//    hA @ floats 0..31, hB @ 48..79 (bank offset 16): per-half broadcast
//    ds_read_b128 groups hit disjoint banks; h-write is 2 lanes/bank.
//  - x: per-half-uniform GLOBAL broadcast loads (3 b32/step) - x moves off
//    the LDS pipe (now the binding resource) onto VMEM; L1/L2 resident.
//  - 1024 blocks x 64 thr = 1 wave/SIMD; __launch_bounds__(64,1).

#define GRU_B 2048
#define GRU_T 2048
#define GRU_D 3
#define GRU_H 32
#define CHUNK 32  // output batching only

// s_waitcnt imm: lgkmcnt(0), vmcnt=63 (no wait), expcnt=7 (no wait)
#define WAIT_LGKM0 0xC07F

__device__ __forceinline__ float fast_sigmoid(float x) {
    float e = __expf(-x);                    // v_mul(log2e)+v_exp
    return __builtin_amdgcn_rcpf(1.0f + e);  // e=inf -> 0 (correct limit)
}
__device__ __forceinline__ float fast_tanh(float x) {
    float e = __expf(2.0f * x);              // overflow -> inf -> tanh=1
    return 1.0f - 2.0f * __builtin_amdgcn_rcpf(e + 1.0f);
}

__global__ __launch_bounds__(64, 1) void gru_scan_kernel(
    const float* __restrict__ inp,     // [B, T, D]
    const float* __restrict__ w_ih,    // [3H, D]
    const float* __restrict__ w_hh,    // [3H, H]
    const float* __restrict__ bias,    // [3H]
    const float* __restrict__ bias_n,  // [H]
    float* __restrict__ out)           // [B, T]
{
    // h storage: seq-A h at floats [0..31], seq-B h at [48..79]
    // (start%32 = 16 -> disjoint bank groups vs A for every b128 quad).
    __shared__ __align__(16) float h2[80];

    const int lane = threadIdx.x;   // 0..63
    const int p    = lane & 31;     // owned hidden unit
    const int hf   = lane >> 5;     // 0: seq 2b, 1: seq 2b+1
    const size_t seq = 2 * (size_t)blockIdx.x + hf;

    // ---- weights for unit p: rows p (r), 32+p (z), 64+p (n) ----
    float wr[32], wz[32], wn[32];
    {
        const float4* pr = (const float4*)(w_hh + (size_t)p * GRU_H);
        const float4* pz = (const float4*)(w_hh + (size_t)(GRU_H + p) * GRU_H);
        const float4* pn = (const float4*)(w_hh + (size_t)(2 * GRU_H + p) * GRU_H);
#pragma unroll
        for (int q = 0; q < 8; ++q) {
            float4 R = pr[q], Z = pz[q], N = pn[q];
            wr[4*q+0]=R.x; wr[4*q+1]=R.y; wr[4*q+2]=R.z; wr[4*q+3]=R.w;
            wz[4*q+0]=Z.x; wz[4*q+1]=Z.y; wz[4*q+2]=Z.z; wz[4*q+3]=Z.w;
            wn[4*q+0]=N.x; wn[4*q+1]=N.y; wn[4*q+2]=N.z; wn[4*q+3]=N.w;
        }
    }
    float wir[GRU_D], wiz[GRU_D], win[GRU_D];
#pragma unroll
    for (int d = 0; d < GRU_D; ++d) {
        wir[d] = w_ih[(size_t)p * GRU_D + d];
        wiz[d] = w_ih[(size_t)(GRU_H + p) * GRU_D + d];
        win[d] = w_ih[(size_t)(2 * GRU_H + p) * GRU_D + d];
    }
    const float bR = bias[p];
    const float bZ = bias[GRU_H + p];
    const float bN = bias[2 * GRU_H + p] + bias_n[p];

    const float* xp = inp + seq * (size_t)(GRU_T * GRU_D);  // per-half uniform
    float*       ob = out + seq * (size_t)GRU_T;

    const int hbase = 48 * hf;
    float* hw = h2 + hbase + p;                    // my h slot
    const float4* hv = (const float4*)(h2 + hbase);  // my seq's h vector

    float h = 0.0f;
    *hw = 0.0f;  // zero init; same-wave DS order covers the first gather

    for (int c = 0; c < GRU_T / CHUNK; ++c) {
        float outreg = 0.0f;
#pragma unroll 8
        for (int s = 0; s < CHUNK; ++s) {
            const int t = c * CHUNK + s;
            // x broadcast (VMEM, per-half uniform address, L1/L2-resident)
            const float x0 = xp[3 * t + 0];
            const float x1 = xp[3 * t + 1];
            const float x2 = xp[3 * t + 2];

            // h all-gather: 8 x ds_read_b128, broadcast per half,
            // disjoint banks between halves.
            float4 hk[8];
#pragma unroll
            for (int q = 0; q < 8; ++q) hk[q] = hv[q];

            // input projections (independent of h -> fills the lgkm gap)
            const float aR = fmaf(wir[2], x2, fmaf(wir[1], x1, fmaf(wir[0], x0, bR)));
            const float aZ = fmaf(wiz[2], x2, fmaf(wiz[1], x1, fmaf(wiz[0], x0, bZ)));
            const float aN = fmaf(win[2], x2, fmaf(win[1], x1, fmaf(win[0], x0, bN)));

            // 96 FMAs: full K=32 dot for r, z, n rows (2 accs each)
            float r0=0.f, r1=0.f, z0=0.f, z1=0.f, n0=0.f, n1=0.f;
#pragma unroll
            for (int q = 0; q < 8; ++q) {
                const float4 v = hk[q];
                r0 = fmaf(wr[4*q+0], v.x, r0); r1 = fmaf(wr[4*q+1], v.y, r1);
                r0 = fmaf(wr[4*q+2], v.z, r0); r1 = fmaf(wr[4*q+3], v.w, r1);
                z0 = fmaf(wz[4*q+0], v.x, z0); z1 = fmaf(wz[4*q+1], v.y, z1);
                z0 = fmaf(wz[4*q+2], v.z, z0); z1 = fmaf(wz[4*q+3], v.w, z1);
                n0 = fmaf(wn[4*q+0], v.x, n0); n1 = fmaf(wn[4*q+1], v.y, n1);
                n0 = fmaf(wn[4*q+2], v.z, n0); n1 = fmaf(wn[4*q+3], v.w, n1);
            }
            const float rg = fast_sigmoid(aR + (r0 + r1));
            const float zg = fast_sigmoid(aZ + (z0 + z1));
            const float ng = fast_tanh(fmaf(rg, n0 + n1, aN));
            const float hnew = fmaf(zg, h - ng, ng);   // (1-z)*n + z*h

            // hk[0].x = h[0] BEFORE this step = output of step s-1 (own seq)
            if (p == s - 1) outreg = hk[0].x;

            h = hnew;
            *hw = h;  // next gather is ordered behind this write (same wave)
        }
        // output of step 31: h[0] after last step (DS-ordered read)
        {
            const float h0 = h2[hbase];
            if (p == CHUNK - 1) outreg = h0;
        }
        ob[c * CHUNK + p] = outreg;  // 2 x 128B coalesced stores (per half)
    }
}

extern "C" void kernel_launch(void* const* d_in, const int* in_sizes, int n_in,
                              void* d_out, int out_size, void* d_ws, size_t ws_size,
                              hipStream_t stream) {
    const float* inp    = (const float*)d_in[0];
    const float* w_ih   = (const float*)d_in[1];
    const float* w_hh   = (const float*)d_in[2];
    const float* bias   = (const float*)d_in[3];
    const float* bias_n = (const float*)d_in[4];
    float* out = (float*)d_out;

    dim3 grid(GRU_B / 2);
    dim3 block(64);
    gru_scan_kernel<<<grid, block, 0, stream>>>(inp, w_ih, w_hh, bias, bias_n, out);
}